// Round 1
// baseline (899.481 us; speedup 1.0000x reference)
//
#include <hip/hip_runtime.h>
#include <hip/hip_bf16.h>

#define N_NODES 50000
#define N_EDGES 800000
#define IN_CH 64
#define HID_CH 128
#define OUT_CH 64
#define N_GRAPHS 512
#define CHUNK 32

__device__ __forceinline__ void atomAddF(float* p, float v) {
    unsafeAtomicAdd(p, v);  // guaranteed HW global_atomic_add_f32 on gfx950
}

// K1: scatter x[src] into agg[dst], count deg[dst]. 16 lanes/edge, float4 each.
__global__ __launch_bounds__(256) void edge_scatter(
    const float* __restrict__ x, const int* __restrict__ ei,
    float* __restrict__ agg, float* __restrict__ deg)
{
    long long t = (long long)blockIdx.x * blockDim.x + threadIdx.x;
    int e = (int)(t >> 4);
    int l = (int)(t & 15);
    if (e >= N_EDGES) return;
    int src = ei[e];
    int dst = ei[N_EDGES + e];
    const float4 v = *reinterpret_cast<const float4*>(x + (size_t)src * IN_CH + l * 4);
    float* a = agg + (size_t)dst * IN_CH + l * 4;
    atomAddF(a + 0, v.x);
    atomAddF(a + 1, v.y);
    atomAddF(a + 2, v.z);
    atomAddF(a + 3, v.w);
    if (l == 0) atomAddF(deg + dst, 1.0f);
}

// K2: per-node SAGE + attention + pooled scatter (register-accumulated flush).
// 128 threads/block; thread j owns hidden channel j, weight rows in VGPRs.
__global__ __launch_bounds__(128, 2) void node_kernel(
    const float* __restrict__ x, const float* __restrict__ agg,
    const float* __restrict__ deg, const int* __restrict__ batch,
    const float* __restrict__ Wl, const float* __restrict__ bl,
    const float* __restrict__ Wr, const float* __restrict__ Watt,
    const float* __restrict__ batt,
    float* __restrict__ pooled, float* __restrict__ counts)
{
    const int j = threadIdx.x;
    const int n0 = blockIdx.x * CHUNK;
    const int n1 = min(n0 + CHUNK, N_NODES);

    // weight rows -> registers (one-time per block)
    float wl[IN_CH], wr[IN_CH];
#pragma unroll
    for (int c4 = 0; c4 < IN_CH / 4; ++c4) {
        float4 a = *reinterpret_cast<const float4*>(Wl + (size_t)j * IN_CH + c4 * 4);
        wl[c4 * 4 + 0] = a.x; wl[c4 * 4 + 1] = a.y; wl[c4 * 4 + 2] = a.z; wl[c4 * 4 + 3] = a.w;
        float4 b = *reinterpret_cast<const float4*>(Wr + (size_t)j * IN_CH + c4 * 4);
        wr[c4 * 4 + 0] = b.x; wr[c4 * 4 + 1] = b.y; wr[c4 * 4 + 2] = b.z; wr[c4 * 4 + 3] = b.w;
    }
    const float blj = bl[j];
    const float wa  = Watt[j];
    const float ba  = batt[0];

    __shared__ __align__(16) float sx[IN_CH];
    __shared__ __align__(16) float sa[IN_CH];
    __shared__ float sred[2];

    float accp = 0.0f;   // pooled accumulator, channel j, current graph
    float cnt  = 0.0f;
    int curb = batch[n0];

    for (int n = n0; n < n1; ++n) {
        __syncthreads();  // protect sx/sa/sred from previous iteration's readers
        if (j < IN_CH) {
            sx[j] = x[(size_t)n * IN_CH + j];
        } else {
            float inv = 1.0f / fmaxf(deg[n], 1.0f);
            sa[j - IN_CH] = agg[(size_t)n * IN_CH + (j - IN_CH)] * inv;
        }
        __syncthreads();

        float h = blj;
#pragma unroll
        for (int c4 = 0; c4 < IN_CH / 4; ++c4) {
            float4 xv = *reinterpret_cast<const float4*>(&sx[c4 * 4]);
            float4 av = *reinterpret_cast<const float4*>(&sa[c4 * 4]);
            h += wl[c4 * 4 + 0] * av.x + wl[c4 * 4 + 1] * av.y
               + wl[c4 * 4 + 2] * av.z + wl[c4 * 4 + 3] * av.w;
            h += wr[c4 * 4 + 0] * xv.x + wr[c4 * 4 + 1] * xv.y
               + wr[c4 * 4 + 2] * xv.z + wr[c4 * 4 + 3] * xv.w;
        }
        h = fmaxf(h, 0.0f);

        // score = sigmoid(sum_j Watt[j]*h[j] + b_att)
        float r = wa * h;
#pragma unroll
        for (int off = 32; off >= 1; off >>= 1) r += __shfl_down(r, off);
        if ((j & 63) == 0) sred[j >> 6] = r;
        __syncthreads();
        float score = 1.0f / (1.0f + expf(-(sred[0] + sred[1] + ba)));
        float hs = h * score;

        int b = batch[n];  // uniform across block
        if (b != curb) {   // flush accumulated graph (batch is sorted)
            atomAddF(&pooled[(size_t)curb * HID_CH + j], accp);
            if (j == 0) atomAddF(&counts[curb], cnt);
            accp = 0.0f; cnt = 0.0f; curb = b;
        }
        accp += hs;
        if (j == 0) cnt += 1.0f;
    }
    atomAddF(&pooled[(size_t)curb * HID_CH + j], accp);
    if (j == 0) atomAddF(&counts[curb], cnt);
}

// K3: out[g][j] = bout[j] + sum_c Wout[j][c] * pooled_mean[g][c]
__global__ __launch_bounds__(64) void out_kernel(
    const float* __restrict__ pooled, const float* __restrict__ counts,
    const float* __restrict__ Wout, const float* __restrict__ bout,
    float* __restrict__ out)
{
    const int g = blockIdx.x;
    const int j = threadIdx.x;  // 0..63
    __shared__ __align__(16) float sp[HID_CH];
    float inv = 1.0f / fmaxf(counts[g], 1.0f);
    sp[j]      = pooled[(size_t)g * HID_CH + j] * inv;
    sp[j + 64] = pooled[(size_t)g * HID_CH + 64 + j] * inv;
    __syncthreads();
    float acc = bout[j];
#pragma unroll
    for (int c4 = 0; c4 < HID_CH / 4; ++c4) {
        float4 w = *reinterpret_cast<const float4*>(Wout + (size_t)j * HID_CH + c4 * 4);
        acc += w.x * sp[c4 * 4 + 0] + w.y * sp[c4 * 4 + 1]
             + w.z * sp[c4 * 4 + 2] + w.w * sp[c4 * 4 + 3];
    }
    out[(size_t)g * OUT_CH + j] = acc;
}

extern "C" void kernel_launch(void* const* d_in, const int* in_sizes, int n_in,
                              void* d_out, int out_size, void* d_ws, size_t ws_size,
                              hipStream_t stream)
{
    const float* x     = (const float*)d_in[0];
    const int*   ei    = (const int*)d_in[1];
    const int*   batch = (const int*)d_in[2];
    const float* Wl    = (const float*)d_in[3];
    const float* bl    = (const float*)d_in[4];
    const float* Wr    = (const float*)d_in[5];
    const float* Watt  = (const float*)d_in[6];
    const float* batt  = (const float*)d_in[7];
    const float* Wout  = (const float*)d_in[8];
    const float* bout  = (const float*)d_in[9];
    float* out = (float*)d_out;

    // workspace layout (contiguous so one memset covers it)
    float* agg    = (float*)d_ws;
    float* deg    = agg + (size_t)N_NODES * IN_CH;
    float* pooled = deg + N_NODES;
    float* counts = pooled + (size_t)N_GRAPHS * HID_CH;
    size_t zero_bytes = ((size_t)N_NODES * IN_CH + N_NODES
                       + (size_t)N_GRAPHS * HID_CH + N_GRAPHS) * sizeof(float);
    hipMemsetAsync(d_ws, 0, zero_bytes, stream);

    edge_scatter<<<(N_EDGES * 16 + 255) / 256, 256, 0, stream>>>(x, ei, agg, deg);
    node_kernel<<<(N_NODES + CHUNK - 1) / CHUNK, 128, 0, stream>>>(
        x, agg, deg, batch, Wl, bl, Wr, Watt, batt, pooled, counts);
    out_kernel<<<N_GRAPHS, 64, 0, stream>>>(pooled, counts, Wout, bout, out);
}

// Round 3
// 389.528 us; speedup vs baseline: 2.3092x; 2.3092x over previous
//
#include <hip/hip_runtime.h>
#include <hip/hip_bf16.h>

#define N_NODES 50000
#define N_EDGES 800000
#define IN_CH 64
#define HID_CH 128
#define OUT_CH 64
#define N_GRAPHS 512
#define CHUNK 32

__device__ __forceinline__ void atomAddF(float* p, float v) {
    unsafeAtomicAdd(p, v);  // HW global_atomic_add_f32 on gfx950
}

// ---- Edge phase: CSR build (int atomics only) + deterministic gather ----

// K1: degree histogram
__global__ __launch_bounds__(256) void hist_kernel(
    const int* __restrict__ ei, int* __restrict__ degi)
{
    int e = blockIdx.x * 256 + threadIdx.x;
    if (e >= N_EDGES) return;
    atomicAdd(&degi[ei[N_EDGES + e]], 1);
}

// K2: exclusive scan of degi -> rowptr. Single block, 1024 threads.
__global__ __launch_bounds__(1024) void scan_kernel(
    const int* __restrict__ degi, int* __restrict__ rowptr)
{
    __shared__ int tot[1024];
    const int t = threadIdx.x;
    const int PER = (N_NODES + 1023) / 1024;  // 49
    int base = t * PER;
    int s = 0;
    for (int i = 0; i < PER; ++i) {
        int idx = base + i;
        if (idx < N_NODES) s += degi[idx];
    }
    tot[t] = s;
    __syncthreads();
    for (int off = 1; off < 1024; off <<= 1) {
        int v = (t >= off) ? tot[t - off] : 0;
        __syncthreads();
        tot[t] += v;
        __syncthreads();
    }
    int run = (t > 0) ? tot[t - 1] : 0;
    for (int i = 0; i < PER; ++i) {
        int idx = base + i;
        if (idx < N_NODES) { rowptr[idx] = run; run += degi[idx]; }
    }
}

// K3: scatter src indices into CSR buckets. rowptr doubles as the cursor:
// after this kernel, rowptr[n] == bucket END (start + deg).
__global__ __launch_bounds__(256) void scatter_csr(
    const int* __restrict__ ei, int* __restrict__ rowptr,
    int* __restrict__ csr)
{
    int e = blockIdx.x * 256 + threadIdx.x;
    if (e >= N_EDGES) return;
    int src = ei[e];
    int dst = ei[N_EDGES + e];
    int pos = atomicAdd(&rowptr[dst], 1);
    csr[pos] = src;
}

// K4: per-node MEAN gather (output is already divided by degree).
// One wave per node; 4 lane-groups of 16 process 4 neighbors concurrently.
__global__ __launch_bounds__(256) void gather_kernel(
    const float* __restrict__ x, const int* __restrict__ csr,
    const int* __restrict__ rowptr, const int* __restrict__ degi,
    float* __restrict__ agg)
{
    int wid  = (blockIdx.x * 256 + threadIdx.x) >> 6;  // node id
    int lane = threadIdx.x & 63;
    if (wid >= N_NODES) return;
    int d   = degi[wid];
    int beg = rowptr[wid] - d;   // rowptr[n] is bucket end after scatter_csr
    int g   = lane >> 4;
    int c4  = lane & 15;
    float4 acc = make_float4(0.f, 0.f, 0.f, 0.f);
    for (int i = g; i < d; i += 4) {
        int src = csr[beg + i];
        float4 v = *reinterpret_cast<const float4*>(x + (size_t)src * IN_CH + c4 * 4);
        acc.x += v.x; acc.y += v.y; acc.z += v.z; acc.w += v.w;
    }
    acc.x += __shfl_xor(acc.x, 16); acc.y += __shfl_xor(acc.y, 16);
    acc.z += __shfl_xor(acc.z, 16); acc.w += __shfl_xor(acc.w, 16);
    acc.x += __shfl_xor(acc.x, 32); acc.y += __shfl_xor(acc.y, 32);
    acc.z += __shfl_xor(acc.z, 32); acc.w += __shfl_xor(acc.w, 32);
    if (g == 0) {
        float inv = 1.0f / fmaxf((float)d, 1.0f);
        acc.x *= inv; acc.y *= inv; acc.z *= inv; acc.w *= inv;
        *reinterpret_cast<float4*>(agg + (size_t)wid * IN_CH + c4 * 4) = acc;
    }
}

// ---- Node phase: SAGE + attention + pooled scatter ----
// agg is ALREADY the neighbor mean — no division here.
__global__ __launch_bounds__(128, 2) void node_kernel(
    const float* __restrict__ x, const float* __restrict__ agg,
    const int* __restrict__ batch,
    const float* __restrict__ Wl, const float* __restrict__ bl,
    const float* __restrict__ Wr, const float* __restrict__ Watt,
    const float* __restrict__ batt,
    float* __restrict__ pooled, float* __restrict__ counts)
{
    const int j = threadIdx.x;
    const int n0 = blockIdx.x * CHUNK;
    const int n1 = min(n0 + CHUNK, N_NODES);

    float wl[IN_CH], wr[IN_CH];
#pragma unroll
    for (int c4 = 0; c4 < IN_CH / 4; ++c4) {
        float4 a = *reinterpret_cast<const float4*>(Wl + (size_t)j * IN_CH + c4 * 4);
        wl[c4 * 4 + 0] = a.x; wl[c4 * 4 + 1] = a.y; wl[c4 * 4 + 2] = a.z; wl[c4 * 4 + 3] = a.w;
        float4 b = *reinterpret_cast<const float4*>(Wr + (size_t)j * IN_CH + c4 * 4);
        wr[c4 * 4 + 0] = b.x; wr[c4 * 4 + 1] = b.y; wr[c4 * 4 + 2] = b.z; wr[c4 * 4 + 3] = b.w;
    }
    const float blj = bl[j];
    const float wa  = Watt[j];
    const float ba  = batt[0];

    __shared__ __align__(16) float sx[IN_CH];
    __shared__ __align__(16) float sa[IN_CH];
    __shared__ float sred[2];

    float accp = 0.0f;
    float cnt  = 0.0f;
    int curb = batch[n0];

    for (int n = n0; n < n1; ++n) {
        __syncthreads();
        if (j < IN_CH) {
            sx[j] = x[(size_t)n * IN_CH + j];
        } else {
            sa[j - IN_CH] = agg[(size_t)n * IN_CH + (j - IN_CH)];
        }
        __syncthreads();

        float h = blj;
#pragma unroll
        for (int c4 = 0; c4 < IN_CH / 4; ++c4) {
            float4 xv = *reinterpret_cast<const float4*>(&sx[c4 * 4]);
            float4 av = *reinterpret_cast<const float4*>(&sa[c4 * 4]);
            h += wl[c4 * 4 + 0] * av.x + wl[c4 * 4 + 1] * av.y
               + wl[c4 * 4 + 2] * av.z + wl[c4 * 4 + 3] * av.w;
            h += wr[c4 * 4 + 0] * xv.x + wr[c4 * 4 + 1] * xv.y
               + wr[c4 * 4 + 2] * xv.z + wr[c4 * 4 + 3] * xv.w;
        }
        h = fmaxf(h, 0.0f);

        float r = wa * h;
#pragma unroll
        for (int off = 32; off >= 1; off >>= 1) r += __shfl_down(r, off);
        if ((j & 63) == 0) sred[j >> 6] = r;
        __syncthreads();
        float score = 1.0f / (1.0f + expf(-(sred[0] + sred[1] + ba)));
        float hs = h * score;

        int b = batch[n];
        if (b != curb) {
            atomAddF(&pooled[(size_t)curb * HID_CH + j], accp);
            if (j == 0) atomAddF(&counts[curb], cnt);
            accp = 0.0f; cnt = 0.0f; curb = b;
        }
        accp += hs;
        if (j == 0) cnt += 1.0f;
    }
    atomAddF(&pooled[(size_t)curb * HID_CH + j], accp);
    if (j == 0) atomAddF(&counts[curb], cnt);
}

// K6: out[g][j] = bout[j] + sum_c Wout[j][c] * pooled_mean[g][c]
__global__ __launch_bounds__(64) void out_kernel(
    const float* __restrict__ pooled, const float* __restrict__ counts,
    const float* __restrict__ Wout, const float* __restrict__ bout,
    float* __restrict__ out)
{
    const int g = blockIdx.x;
    const int j = threadIdx.x;
    __shared__ __align__(16) float sp[HID_CH];
    float inv = 1.0f / fmaxf(counts[g], 1.0f);
    sp[j]      = pooled[(size_t)g * HID_CH + j] * inv;
    sp[j + 64] = pooled[(size_t)g * HID_CH + 64 + j] * inv;
    __syncthreads();
    float acc = bout[j];
#pragma unroll
    for (int c4 = 0; c4 < HID_CH / 4; ++c4) {
        float4 w = *reinterpret_cast<const float4*>(Wout + (size_t)j * HID_CH + c4 * 4);
        acc += w.x * sp[c4 * 4 + 0] + w.y * sp[c4 * 4 + 1]
             + w.z * sp[c4 * 4 + 2] + w.w * sp[c4 * 4 + 3];
    }
    out[(size_t)g * OUT_CH + j] = acc;
}

extern "C" void kernel_launch(void* const* d_in, const int* in_sizes, int n_in,
                              void* d_out, int out_size, void* d_ws, size_t ws_size,
                              hipStream_t stream)
{
    const float* x     = (const float*)d_in[0];
    const int*   ei    = (const int*)d_in[1];
    const int*   batch = (const int*)d_in[2];
    const float* Wl    = (const float*)d_in[3];
    const float* bl    = (const float*)d_in[4];
    const float* Wr    = (const float*)d_in[5];
    const float* Watt  = (const float*)d_in[6];
    const float* batt  = (const float*)d_in[7];
    const float* Wout  = (const float*)d_in[8];
    const float* bout  = (const float*)d_in[9];
    float* out = (float*)d_out;

    // workspace layout: [zeroed region | uninitialized region]
    int*   degi   = (int*)d_ws;                                   // zero
    float* pooled = (float*)(degi + N_NODES);                     // zero
    float* counts = pooled + (size_t)N_GRAPHS * HID_CH;           // zero
    int*   rowptr = (int*)(counts + N_GRAPHS);                    // written by scan
    int*   csr    = rowptr + N_NODES;                             // written by scatter
    float* agg    = (float*)(csr + N_EDGES);                      // fully overwritten

    size_t zero_bytes = ((size_t)N_NODES
                       + (size_t)N_GRAPHS * HID_CH + N_GRAPHS) * sizeof(int);
    hipMemsetAsync(d_ws, 0, zero_bytes, stream);

    hist_kernel<<<(N_EDGES + 255) / 256, 256, 0, stream>>>(ei, degi);
    scan_kernel<<<1, 1024, 0, stream>>>(degi, rowptr);
    scatter_csr<<<(N_EDGES + 255) / 256, 256, 0, stream>>>(ei, rowptr, csr);
    gather_kernel<<<(N_NODES * 64 + 255) / 256, 256, 0, stream>>>(x, csr, rowptr, degi, agg);
    node_kernel<<<(N_NODES + CHUNK - 1) / CHUNK, 128, 0, stream>>>(
        x, agg, batch, Wl, bl, Wr, Watt, batt, pooled, counts);
    out_kernel<<<N_GRAPHS, 64, 0, stream>>>(pooled, counts, Wout, bout, out);
}